// Round 7
// baseline (177.622 us; speedup 1.0000x reference)
//
#include <hip/hip_runtime.h>
#include <math.h>

#define C 100
#define RPP 16                         // rows per wave (one pass, short waves)
#define WAVES 4                        // waves per 256-thread block
#define ROWS_PER_BLOCK (WAVES * RPP)   // 64
#define NF4P (RPP * C / 4)             // 400 float4 per wave
#define INV_NORM 0.3989422804014327f   // 1/sqrt(2*pi), STD = 1
#define WFAR     0.67102943f           // exp(-inv_norm) = lim w(d)

// quad (4-lane) sum via DPP quad_perm — VALU only, no DS pipe
__device__ __forceinline__ float quad_sum(float x) {
    x += __int_as_float(__builtin_amdgcn_update_dpp(
            0, __float_as_int(x), 0xB1, 0xF, 0xF, true));  // [1,0,3,2]
    x += __int_as_float(__builtin_amdgcn_update_dpp(
            0, __float_as_int(x), 0x4E, 0xF, 0xF, true));  // [2,3,0,1]
    return x;
}

// Math (verified rounds 4-6): w(d) = exp(code(d)-inv_norm),
// code(d) = inv_norm*exp(-d^2/2); w'(d) = w(d)-wfar, zero for |d|>6.
//   csum = 100*wfar + sum_{valid d} w'(|d|)
//   dot  = wfar*rowsum + sum_{|d|<=6} w'(d) s_{mu+d}
//   dotc = sum_{valid d} w(|d|)*code(|d|)
//   kl_row = (dotc - dot)/csum - inv_norm - log(csum) + log(sum_j exp s_j)
// (scores ~ N(0,1): exp(s) safe in fp32 without max-subtraction)
//
// Structure: SHORT waves, heavy churn. Each wave: 8 coalesced loads ->
// wave-private LDS slice (no __syncthreads; per-wave DS ops in-order) ->
// quad-per-row compute -> DPP reduce -> 1 atomic/block. 4096 blocks,
// 6 blocks/CU resident (LDS-limited), 16 blocks/CU churned sequentially:
// retiring blocks keep fresh loads entering the memory system (the issue
// pattern the 6.8 TB/s harness fills have and long-lived waves don't).
__global__ __launch_bounds__(256, 6) void kl_main(
    const float* __restrict__ scores,
    const int*   __restrict__ labels,
    float* __restrict__ out, int n, float inv_n)
{
    __shared__ float sl[WAVES][RPP * C];   // 4 x 6400 B, wave-private
    __shared__ float wpart[WAVES];

    const int tid  = threadIdx.x;
    const int wave = tid >> 6, lane = tid & 63;
    const int r    = lane >> 2, sub  = lane & 3;   // quad r owns row r
    float* const mys = sl[wave];

    const int rowBase = blockIdx.x * ROWS_PER_BLOCK + wave * RPP;
    const int myrow   = rowBase + r;

    // labels first (latency hides under score loads)
    const int mu = (myrow < n) ? labels[myrow] : 0;

    // 16 rows = 400 float4: 7 coalesced wave-loads (1 KB/instr), in flight
    const int nf4 = min(RPP, max(0, n - rowBase)) * (C / 4);
    const float4* g = (const float4*)(scores + (size_t)rowBase * C);
    float4 v[7];
    #pragma unroll
    for (int c = 0; c < 7; ++c) {
        int i = lane + 64 * c;
        v[c] = (i < nf4) ? g[i] : make_float4(0.f, 0.f, 0.f, 0.f);
    }

    // stage to wave-private LDS (contiguous ds_write_b128, conflict-free)
    float4* st = (float4*)mys;
    #pragma unroll
    for (int c = 0; c < 7; ++c) {
        int i = lane + 64 * c;
        if (i < NF4P) st[i] = v[c];
    }

    // --- quad-per-row compute ---
    const float* sp  = &mys[r * C];
    const float* spl = sp + sub * 25;   // 2 lanes/bank: free
    float se = 0.f, rs = 0.f;
    #pragma unroll
    for (int i = 0; i < 25; ++i) {
        float s = spl[i];
        se += __expf(s);
        rs += s;
    }
    se = quad_sum(se);
    rs = quad_sum(rs);

    // 13-term window around mu, redundantly on all 4 lanes (LDS broadcasts)
    const float WP[7] = {0.32897057f, 0.18369895f, 0.03722540f,
        0.00298049f, 8.9804e-5f, 9.9763e-7f, 4.0768e-9f};
    const float WC[7] = {0.39894228f, 0.20681926f, 0.03823936f,
        0.00298711f, 8.9816e-5f, 9.9765e-7f, 4.0768e-9f};
    float dotw = 0.f, csum = 100.f * WFAR, dotc = 0.f;
    #pragma unroll
    for (int d = -6; d <= 6; ++d) {
        int idx  = mu + d;
        bool ok  = (unsigned)idx < (unsigned)C;
        float s  = sp[min(max(idx, 0), C - 1)];
        int a    = d < 0 ? -d : d;               // compile-time
        float wv = ok ? WP[a] : 0.f;
        dotw  = fmaf(wv, s, dotw);
        csum += wv;
        dotc += ok ? WC[a] : 0.f;
    }

    float acc = 0.f;
    if (sub == 0 && myrow < n) {
        float dot = fmaf(WFAR, rs, dotw);
        acc = (dotc - dot) / csum - INV_NORM - __logf(csum) + __logf(se);
    }

    // wave reduce (only sub==0 lanes nonzero) + block combine, 1 atomic/block
    #pragma unroll
    for (int off = 32; off > 0; off >>= 1)
        acc += __shfl_xor(acc, off, 64);
    if (lane == 0) wpart[wave] = acc;
    __syncthreads();
    if (tid == 0)
        atomicAdd(out, (wpart[0] + wpart[1] + wpart[2] + wpart[3]) * inv_n);
}

extern "C" void kernel_launch(void* const* d_in, const int* in_sizes, int n_in,
                              void* d_out, int out_size, void* d_ws, size_t ws_size,
                              hipStream_t stream)
{
    const float* scores = (const float*)d_in[0];
    const int*   labels = (const int*)d_in[1];
    float*       out    = (float*)d_out;

    int n = in_sizes[0] / C;   // 262144

    // d_out is poisoned (0xAA) before every timed launch — zero it first.
    hipMemsetAsync(d_out, 0, sizeof(float) * (size_t)out_size, stream);

    int blocks = (n + ROWS_PER_BLOCK - 1) / ROWS_PER_BLOCK;   // 4096
    kl_main<<<blocks, 256, 0, stream>>>(scores, labels, out, n, 1.0f / (float)n);
}

// Round 9
// 162.986 us; speedup vs baseline: 1.0898x; 1.0898x over previous
//
#include <hip/hip_runtime.h>
#include <math.h>

#define C 100
#define PAIRS 8                          // row-pairs per pass per wave
#define PASSES 2
#define ROWS_PER_WAVE  (2 * PAIRS * PASSES)        // 32
#define ROWS_PER_BLOCK (4 * ROWS_PER_WAVE)         // 128
#define INV_NORM 0.3989422804014327f     // 1/sqrt(2*pi), STD = 1
#define WFAR     0.67102943f             // exp(-inv_norm) = lim w(d)

// w'(a) = exp(code(a)-inv_norm)-wfar ; wc(a) = w(a)*code(a)
__device__ __constant__ float WPc[7] = {0.32897057f, 0.18369895f, 0.03722540f,
    0.00298049f, 8.9804e-5f, 9.9763e-7f, 4.0768e-9f};
__device__ __constant__ float WCc[7] = {0.39894228f, 0.20681926f, 0.03823936f,
    0.00298711f, 8.9816e-5f, 9.9765e-7f, 4.0768e-9f};

// dpp ctrl must be an ICE at the builtin call site -> template parameter
template <int CTRL>
__device__ __forceinline__ float dpp_add(float x) {
    return x + __int_as_float(__builtin_amdgcn_update_dpp(
        0, __float_as_int(x), CTRL, 0xF, 0xF, true));
}
// 32-lane-group sum, VALU-only. Result valid in lanes 28-31 / 60-63.
__device__ __forceinline__ float group32_sum(float x) {
    x = dpp_add<0xB1>(x);    // quad_perm [1,0,3,2]
    x = dpp_add<0x4E>(x);    // quad_perm [2,3,0,1]
    x = dpp_add<0x118>(x);   // row_shr:8 (lanes 12-15 of each 16-row = row sum)
    x = dpp_add<0x114>(x);   // row_shr:4
    x = dpp_add<0x142>(x);   // row_bcast15 (lane15->16..31, lane47->48..63)
    return x;
}

// One row per HALF-WAVE, loaded straight to VGPRs (no LDS round trip):
// lanes 0-24 hold row 2p's 25 float4s, lanes 32-56 row 2p+1's. Loads are
// line-coalesced (4 x 128B lines/instr). Masked lanes load 0 -> exp(0)=1,
// corrected exactly by se-28. Row math (verified R4-R7):
//   kl_row = K(mu) + log(se) - rcs(mu) * (wfar*rowsum + sum w'(d) s_{mu+d})
//   K(mu)  = dotc/csum - inv_norm - log(csum),  rcs = 1/csum  (LDS tables)
__global__ __launch_bounds__(256, 6) void kl_main(
    const float* __restrict__ scores,
    const int*   __restrict__ labels,
    float* __restrict__ out, int n, float inv_n)
{
    __shared__ float Ktab[C], Rtab[C], wq[16];
    __shared__ float wpart[4];

    const int tid = threadIdx.x;
    // --- one-time per block: per-label tables ---
    if (tid < C) {
        float csum = (float)C * WFAR, dotc = 0.f;
        #pragma unroll
        for (int d = -6; d <= 6; ++d) {
            bool ok = (unsigned)(tid + d) < (unsigned)C;
            int a = d < 0 ? -d : d;
            csum += ok ? WPc[a] : 0.f;
            dotc += ok ? WCc[a] : 0.f;
        }
        Rtab[tid] = 1.0f / csum;
        Ktab[tid] = dotc / csum - INV_NORM - __logf(csum);
    }
    if (tid < 16) wq[tid] = (tid < 7) ? WPc[tid] : 0.f;
    __syncthreads();

    const int wave = tid >> 6, lane = tid & 63;
    const int sub  = lane & 31;        // float4 index within row (0..24 active)
    const int half = lane >> 5;        // 0: row 2p, 1: row 2p+1
    const int waveRow0 = blockIdx.x * ROWS_PER_BLOCK + wave * ROWS_PER_WAVE;
    const float4* g4 = (const float4*)scores;

    float acc = 0.f;

    for (int pass = 0; pass < PASSES; ++pass) {
        const int base = waveRow0 + pass * (2 * PAIRS);

        // --- issue: 8 predicated row-pair loads + labels, all in flight ---
        float4 v[PAIRS]; int mu[PAIRS];
        #pragma unroll
        for (int p = 0; p < PAIRS; ++p) {
            int row = base + 2 * p + half;
            bool ok = (sub < 25) && (row < n);
            v[p]  = ok ? g4[(size_t)row * 25 + sub]
                       : make_float4(0.f, 0.f, 0.f, 0.f);
            mu[p] = (row < n) ? labels[row] : 0;
        }

        // --- consume in order (register deps give fine-grained vmcnt) ---
        #pragma unroll
        for (int p = 0; p < PAIRS; ++p) {
            float se = __expf(v[p].x) + __expf(v[p].y)
                     + __expf(v[p].z) + __expf(v[p].w);
            float rs = v[p].x + v[p].y + v[p].z + v[p].w;

            // window dot partial: weights via 16-entry broadcast table
            const int jb = 4 * sub;
            const float el[4] = {v[p].x, v[p].y, v[p].z, v[p].w};
            float dotw = 0.f;
            #pragma unroll
            for (int cmp = 0; cmp < 4; ++cmp) {
                int d = jb + cmp - mu[p];
                int a = min(d < 0 ? -d : d, 15);   // wq[7..15] = 0
                dotw = fmaf(wq[a], el[cmp], dotw);
            }
            float q = fmaf(WFAR, rs, dotw);        // per-lane dot partial

            float seR = group32_sum(se);           // lanes 28-31 / 60-63
            float qR  = group32_sum(q);

            int row = base + 2 * p + half;
            if ((lane == 28 || lane == 60) && row < n)
                acc += Ktab[mu[p]] + __logf(seR - 28.f) - Rtab[mu[p]] * qR;
        }
    }

    // wave reduce (acc nonzero on 2 lanes) + block combine, 1 atomic/block
    #pragma unroll
    for (int off = 32; off > 0; off >>= 1)
        acc += __shfl_xor(acc, off, 64);
    if (lane == 0) wpart[wave] = acc;
    __syncthreads();
    if (tid == 0)
        atomicAdd(out, (wpart[0] + wpart[1] + wpart[2] + wpart[3]) * inv_n);
}

extern "C" void kernel_launch(void* const* d_in, const int* in_sizes, int n_in,
                              void* d_out, int out_size, void* d_ws, size_t ws_size,
                              hipStream_t stream)
{
    const float* scores = (const float*)d_in[0];
    const int*   labels = (const int*)d_in[1];
    float*       out    = (float*)d_out;

    int n = in_sizes[0] / C;   // 262144

    // d_out is poisoned (0xAA) before every timed launch — zero it first.
    (void)hipMemsetAsync(d_out, 0, sizeof(float) * (size_t)out_size, stream);

    int blocks = (n + ROWS_PER_BLOCK - 1) / ROWS_PER_BLOCK;   // 2048
    kl_main<<<blocks, 256, 0, stream>>>(scores, labels, out, n, 1.0f / (float)n);
}

// Round 10
// 156.214 us; speedup vs baseline: 1.1370x; 1.0434x over previous
//
#include <hip/hip_runtime.h>
#include <math.h>

#define C 100
#define RPP 16                         // rows per wave (one pass, short waves)
#define WAVES 4                        // waves per 256-thread block
#define ROWS_PER_BLOCK (WAVES * RPP)   // 64
#define NF4P (RPP * C / 4)             // 400 float4 per wave
#define INV_NORM 0.3989422804014327f   // 1/sqrt(2*pi), STD = 1
#define WFAR     0.67102943f           // exp(-inv_norm) = lim w(d)

// quad (4-lane) sum via DPP quad_perm — VALU only, no DS pipe
template <int CTRL>
__device__ __forceinline__ float dpp_add(float x) {
    return x + __int_as_float(__builtin_amdgcn_update_dpp(
        0, __float_as_int(x), CTRL, 0xF, 0xF, true));
}
__device__ __forceinline__ float quad_sum(float x) {
    x = dpp_add<0xB1>(x);   // [1,0,3,2]
    x = dpp_add<0x4E>(x);   // [2,3,0,1]
    return x;
}

// Math (verified R4-R9): w(d) = exp(code(d)-inv_norm),
// code(d) = inv_norm*exp(-d^2/2); w'(d) = w(d)-wfar, zero for |d|>6.
//   kl_row = (dotc - dot)/csum - inv_norm - log(csum) + log(sum_j exp s_j)
// Structure: R7's short-wave churn (coalesced loads -> wave-private LDS ->
// quad/row compute), but the contended single-word atomicAdd is replaced by
// a per-block partial store to d_ws — blocks retire instantly, no L2
// same-line atomic queue. A 1-block reducer folds the 4096 partials.
__global__ __launch_bounds__(256, 6) void kl_main(
    const float* __restrict__ scores,
    const int*   __restrict__ labels,
    float* __restrict__ part, int n)
{
    __shared__ float sl[WAVES][RPP * C];   // 4 x 6400 B, wave-private
    __shared__ float wpart[WAVES];

    const int tid  = threadIdx.x;
    const int wave = tid >> 6, lane = tid & 63;
    const int r    = lane >> 2, sub  = lane & 3;   // quad r owns row r
    float* const mys = sl[wave];

    const int rowBase = blockIdx.x * ROWS_PER_BLOCK + wave * RPP;
    const int myrow   = rowBase + r;

    const int mu = (myrow < n) ? labels[myrow] : 0;

    // 16 rows = 400 float4: 7 coalesced wave-loads (1 KB/instr), in flight
    const int nf4 = min(RPP, max(0, n - rowBase)) * (C / 4);
    const float4* g = (const float4*)(scores + (size_t)rowBase * C);
    float4 v[7];
    #pragma unroll
    for (int c = 0; c < 7; ++c) {
        int i = lane + 64 * c;
        v[c] = (i < nf4) ? g[i] : make_float4(0.f, 0.f, 0.f, 0.f);
    }

    // stage to wave-private LDS (contiguous ds_write_b128, conflict-free);
    // per-wave DS ops in-order -> no barrier needed
    float4* st = (float4*)mys;
    #pragma unroll
    for (int c = 0; c < 7; ++c) {
        int i = lane + 64 * c;
        if (i < NF4P) st[i] = v[c];
    }

    // --- quad-per-row compute ---
    const float* sp  = &mys[r * C];
    const float* spl = sp + sub * 25;   // 2 lanes/bank: free
    float se = 0.f, rs = 0.f;
    #pragma unroll
    for (int i = 0; i < 25; ++i) {
        float s = spl[i];
        se += __expf(s);
        rs += s;
    }
    se = quad_sum(se);
    rs = quad_sum(rs);

    // 13-term window around mu, redundantly on all 4 lanes (LDS broadcasts)
    const float WP[7] = {0.32897057f, 0.18369895f, 0.03722540f,
        0.00298049f, 8.9804e-5f, 9.9763e-7f, 4.0768e-9f};
    const float WC[7] = {0.39894228f, 0.20681926f, 0.03823936f,
        0.00298711f, 8.9816e-5f, 9.9765e-7f, 4.0768e-9f};
    float dotw = 0.f, csum = 100.f * WFAR, dotc = 0.f;
    #pragma unroll
    for (int d = -6; d <= 6; ++d) {
        int idx  = mu + d;
        bool ok  = (unsigned)idx < (unsigned)C;
        float s  = sp[min(max(idx, 0), C - 1)];
        int a    = d < 0 ? -d : d;               // compile-time
        float wv = ok ? WP[a] : 0.f;
        dotw  = fmaf(wv, s, dotw);
        csum += wv;
        dotc += ok ? WC[a] : 0.f;
    }

    float acc = 0.f;
    if (sub == 0 && myrow < n) {
        float dot = fmaf(WFAR, rs, dotw);
        acc = (dotc - dot) / csum - INV_NORM - __logf(csum) + __logf(se);
    }

    // wave reduce + block partial store (NO atomic — zero contention)
    #pragma unroll
    for (int off = 32; off > 0; off >>= 1)
        acc += __shfl_xor(acc, off, 64);
    if (lane == 0) wpart[wave] = acc;
    __syncthreads();
    if (tid == 0)
        part[blockIdx.x] = wpart[0] + wpart[1] + wpart[2] + wpart[3];
}

// single-block reducer: folds nb partials, writes the final mean
__global__ __launch_bounds__(256) void kl_reduce(
    const float* __restrict__ part, float* __restrict__ out,
    int nb, float inv_n)
{
    __shared__ float w[4];
    float s = 0.f;
    for (int i = threadIdx.x; i < nb; i += 256) s += part[i];
    #pragma unroll
    for (int off = 32; off > 0; off >>= 1)
        s += __shfl_xor(s, off, 64);
    if ((threadIdx.x & 63) == 0) w[threadIdx.x >> 6] = s;
    __syncthreads();
    if (threadIdx.x == 0)
        out[0] = (w[0] + w[1] + w[2] + w[3]) * inv_n;
}

extern "C" void kernel_launch(void* const* d_in, const int* in_sizes, int n_in,
                              void* d_out, int out_size, void* d_ws, size_t ws_size,
                              hipStream_t stream)
{
    const float* scores = (const float*)d_in[0];
    const int*   labels = (const int*)d_in[1];
    float*       part   = (float*)d_ws;    // 4096 floats scratch
    float*       out    = (float*)d_out;

    int n = in_sizes[0] / C;   // 262144
    int blocks = (n + ROWS_PER_BLOCK - 1) / ROWS_PER_BLOCK;   // 4096

    kl_main<<<blocks, 256, 0, stream>>>(scores, labels, part, n);
    kl_reduce<<<1, 256, 0, stream>>>(part, out, blocks, 1.0f / (float)n);
}